// Round 9
// baseline (1490.518 us; speedup 1.0000x reference)
//
#include <hip/hip_runtime.h>
#include <hip/hip_bf16.h>

// MultiTokenPrediction: main head logits + fused CE for main + 2 aux heads.
// B=1, S=2048, D=1024, V=50257, heads predict t+1 (main), t+2, t+3 (aux).

typedef __hip_bfloat16 bf16;
typedef __attribute__((ext_vector_type(8))) short bf16x8;
typedef __attribute__((ext_vector_type(4))) float f32x4;

typedef const __attribute__((address_space(1))) void* gptr_t;
typedef __attribute__((address_space(3))) void* lptr_t;

#define S_LEN   2048
#define DMODEL  1024
#define VOCAB   50257
#define VPAD2   51200   // 200*256 (8x8x25 block swizzle bijective)
#define NT256   200     // VPAD2/256

__device__ __forceinline__ void gload_lds16(const void* g, void* l) {
  __builtin_amdgcn_global_load_lds((gptr_t)g, (lptr_t)l, 16, 0, 0);
}

// ---------------- f32 -> bf16 conversion with row zero-padding ----------------
__global__ __launch_bounds__(256) void k_cvt(const float* __restrict__ src,
                                             bf16* __restrict__ dst,
                                             long rows_src, long rows_pad) {
  const long total4 = rows_pad << 8;
  for (long i = (long)blockIdx.x * 256 + threadIdx.x; i < total4;
       i += (long)gridDim.x * 256) {
    const long e = i << 2;
    const long row = e >> 10;
    alignas(8) bf16 o[4];
    if (row < rows_src) {
      const float4 v = *(const float4*)(src + e);
      o[0] = __float2bfloat16(v.x); o[1] = __float2bfloat16(v.y);
      o[2] = __float2bfloat16(v.z); o[3] = __float2bfloat16(v.w);
    } else {
      o[0] = o[1] = o[2] = o[3] = __float2bfloat16(0.f);
    }
    *(uint2*)(dst + e) = *(const uint2*)o;
  }
}

// ---------------- RMSNorm row kernel: f32 in, bf16 out ----------------
__global__ __launch_bounds__(256) void k_rms(const float* __restrict__ x,
                                             const float* __restrict__ w,
                                             bf16* __restrict__ xn) {
  const int row = blockIdx.x;
  const int t = threadIdx.x;
  const float4 v = ((const float4*)(x + (size_t)row * DMODEL))[t];
  float ss = v.x*v.x + v.y*v.y + v.z*v.z + v.w*v.w;
  #pragma unroll
  for (int d = 1; d < 64; d <<= 1) ss += __shfl_xor(ss, d, 64);
  __shared__ float red[4];
  if ((t & 63) == 0) red[t >> 6] = ss;
  __syncthreads();
  const float tot = red[0] + red[1] + red[2] + red[3];
  const float scale = rsqrtf(tot * (1.f / DMODEL) + 1e-5f);
  const float4 wv = ((const float4*)w)[t];
  alignas(8) bf16 o[4];
  o[0] = __float2bfloat16(v.x * scale * wv.x);
  o[1] = __float2bfloat16(v.y * scale * wv.y);
  o[2] = __float2bfloat16(v.z * scale * wv.z);
  o[3] = __float2bfloat16(v.w * scale * wv.w);
  *(uint2*)(xn + (size_t)row * DMODEL + t * 4) = *(const uint2*)o;
}

// ============ 256x256 bf16 MFMA GEMM: A via LDS, B via REGISTERS ============
// C[m][n] = sum_k A[m][k]*B[n][k]. grid(1600): bm=(id>>3)&7, bn=(id&7)+8*(id>>6)
// (8 bm-siblings share id%8 -> same XCD -> B L2-shared; FETCH 166MB, R4).
// WHY: R3-R8 showed the old 2-operand-LDS loop is LDS-BW-bound (112KB/CU per
// K-half at 85 B/cyc ~= 1318 cyc vs MFMA floor 1242 cyc). B fragments are now
// per-lane global_load_dwordx4 from L2-resident bf16 Wb (lane (q,g) reads
// B[ni*16+q][g*8..+7]; 16x64B segments/instr; wr-twin waves L1-hit), shifting
// B's 2x read amplification off the LDS pipe. LDS = A only: 64KB read +16KB
// write per half << MFMA floor. One barrier per half; 32-MFMA single run.
// A slots=3 rotating 16KB; stage half j+2 during j; end-of-half vmcnt(6)
// (exactly 6 vm-ops issued per half: 4 B-loads then 2 A-stages).
// B regs: 3-deep ring breg[j%3][4] (48 VGPR), loaded 2 halves ahead.
// A layout/swizzle byte-identical to R4 (verified conflict-free R3).
template<bool WRITE_OUT>
__global__ __launch_bounds__(512, 2)
void k_gemm256(const bf16* __restrict__ A, const bf16* __restrict__ B,
               float* __restrict__ C, long ldc, int Nvalid,
               const int* __restrict__ targets, int shift,
               float* __restrict__ pmax, float* __restrict__ psum,
               float* __restrict__ ptgt, int ntiles) {
  __shared__ char lds[3 * 16384 + 9216];

  const int t = threadIdx.x;
  const int w = t >> 6, l = t & 63;
  const int g = l >> 4, q = l & 15;
  const int wr = w >> 2, wc = w & 3;
  const int id = blockIdx.x;
  const int bm = (id >> 3) & 7;
  const int bn = (id & 7) + ((id >> 6) << 3);

  f32x4 acc[8][4];
  #pragma unroll
  for (int i = 0; i < 8; ++i)
    #pragma unroll
    for (int j = 0; j < 4; ++j)
      #pragma unroll
      for (int r = 0; r < 4; ++r) acc[i][j][r] = 0.f;

  // ---- A staging source (bf16; R4-identical) ----
  const int srow = (l >> 2);
  const int scolA = ((l & 3) * 8) ^ (((l >> 5) & 1) * 16);
  const char* gA0 = (const char*)(A + (size_t)(bm * 256 + w * 32 + srow) * DMODEL + scolA);
  const char* gA1 = gA0 + (size_t)16 * DMODEL * 2;

  // ---- B fragment base pointers (per-lane, register path) ----
  const bf16* bp0 = B + (size_t)(bn * 256 + wc * 64 + 0 * 16 + q) * DMODEL + g * 8;
  const bf16* bp1 = B + (size_t)(bn * 256 + wc * 64 + 1 * 16 + q) * DMODEL + g * 8;
  const bf16* bp2 = B + (size_t)(bn * 256 + wc * 64 + 2 * 16 + q) * DMODEL + g * 8;
  const bf16* bp3 = B + (size_t)(bn * 256 + wc * 64 + 3 * 16 + q) * DMODEL + g * 8;

  // ---- A frag-read base (st_16x32-swizzled; R4-identical) ----
  const int laneoffA = (q * 64 + g * 16) ^ (((q >> 3) & 1) << 5);
  const char* rdA = lds + wr * 8192 + laneoffA;

  bf16x8 breg[3][4];   // ring index = half % 3; fully unrolled -> static

  auto stageA = [&](int s, int koff) {
    char* lb = lds + s * 16384 + w * 2048;
    gload_lds16(gA0 + koff, lb);
    gload_lds16(gA1 + koff, lb + 1024);
  };
#define LOADB(RING, HALF) do {                                        \
    breg[RING][0] = *(const bf16x8*)(bp0 + (HALF) * 32);              \
    breg[RING][1] = *(const bf16x8*)(bp1 + (HALF) * 32);              \
    breg[RING][2] = *(const bf16x8*)(bp2 + (HALF) * 32);              \
    breg[RING][3] = *(const bf16x8*)(bp3 + (HALF) * 32);              \
  } while (0)

  // ---- prologue: B0,A0,B1,A1 in flight; drain B0+A0 (6 newest remain) ----
  LOADB(0, 0); stageA(0, 0);
  LOADB(1, 1); stageA(1, 64);
  asm volatile("s_waitcnt vmcnt(6)" ::: "memory");
  __builtin_amdgcn_s_barrier();

  // ---- main loop: 32 K-halves, fully unrolled ----
  #pragma unroll
  for (int j = 0; j < 32; ++j) {
    const int s = j % 3;
    if (j + 2 < 32) {                    // issue next-next half (4 B + 2 A ops)
      LOADB((j + 2) % 3, j + 2);
      stageA((j + 2) % 3, (j + 2) * 64);
    }
    bf16x8 a[8];
    #pragma unroll
    for (int mi = 0; mi < 8; ++mi)
      a[mi] = *(const bf16x8*)(rdA + s * 16384 + mi * 1024);
    __builtin_amdgcn_s_setprio(1);
    #pragma unroll
    for (int mi = 0; mi < 8; ++mi)
      #pragma unroll
      for (int ni = 0; ni < 4; ++ni)
        acc[mi][ni] = __builtin_amdgcn_mfma_f32_16x16x32_bf16(a[mi], breg[s][ni], acc[mi][ni], 0, 0, 0);
    __builtin_amdgcn_s_setprio(0);
    if (j < 30)       { asm volatile("s_waitcnt vmcnt(6)" ::: "memory"); }
    else if (j == 30) { asm volatile("s_waitcnt vmcnt(0)" ::: "memory"); }
    if (j < 31) __builtin_amdgcn_s_barrier();
  }
#undef LOADB

  // ---------------- epilogue: C write ----------------
  if constexpr (WRITE_OUT) {
    #pragma unroll
    for (int mi = 0; mi < 8; ++mi) {
      #pragma unroll
      for (int r = 0; r < 4; ++r) {
        const long row = bm * 256 + wr * 128 + mi * 16 + g * 4 + r;
        #pragma unroll
        for (int ni = 0; ni < 4; ++ni) {
          const int col = bn * 256 + wc * 64 + ni * 16 + q;
          if (col < Nvalid) C[row * ldc + col] = acc[mi][ni][r];
        }
      }
    }
  }

  // ---------------- fused CE partials ----------------
  {
    float* lds_m = (float*)(lds + 3 * 16384);   // [256][4]
    float* lds_s = lds_m + 1024;                // [256][4]
    int* lds_tgt = (int*)(lds_s + 1024);        // [256]
    if (t < 256) {
      const int rowg = bm * 256 + t;
      lds_tgt[t] = (rowg < S_LEN - shift) ? targets[rowg + shift] : -1;
    }
    __syncthreads();
    #pragma unroll
    for (int mi = 0; mi < 8; ++mi) {
      #pragma unroll
      for (int r = 0; r < 4; ++r) {
        const int rl = wr * 128 + mi * 16 + g * 4 + r;
        const int tgt = lds_tgt[rl];
        float v[4];
        #pragma unroll
        for (int ni = 0; ni < 4; ++ni) {
          const int n = bn * 256 + wc * 64 + ni * 16 + q;
          const float av = acc[mi][ni][r];
          if (n == tgt) ptgt[bm * 256 + rl] = av;
          v[ni] = (n < Nvalid) ? av : -1e30f;
        }
        float m = fmaxf(fmaxf(v[0], v[1]), fmaxf(v[2], v[3]));
        #pragma unroll
        for (int d = 1; d < 16; d <<= 1) m = fmaxf(m, __shfl_xor(m, d, 64));
        float s = 0.f;
        #pragma unroll
        for (int ni = 0; ni < 4; ++ni) s += __expf(v[ni] - m);
        #pragma unroll
        for (int d = 1; d < 16; d <<= 1) s += __shfl_xor(s, d, 64);
        if (q == 0) { lds_m[rl * 4 + wc] = m; lds_s[rl * 4 + wc] = s; }
      }
    }
    __syncthreads();
    if (t < 256) {
      float M = lds_m[t * 4 + 0], Ssum = lds_s[t * 4 + 0];
      #pragma unroll
      for (int c = 1; c < 4; ++c) {
        const float m2 = lds_m[t * 4 + c], s2 = lds_s[t * 4 + c];
        const float nM = fmaxf(M, m2);
        Ssum = Ssum * __expf(M - nM) + s2 * __expf(m2 - nM);
        M = nM;
      }
      const size_t idx = (size_t)(bm * 256 + t) * ntiles + bn;
      pmax[idx] = M;
      psum[idx] = Ssum;
    }
  }
}

// ---------------- 128x128 GEMM (small d->d projection) ----------------
__global__ __launch_bounds__(256, 2)
void k_gemm(const bf16* __restrict__ A, const bf16* __restrict__ B,
            float* __restrict__ C, long ldc, int Nvalid) {
  constexpr int K = DMODEL;
  __shared__ bf16 As[128 * 32];
  __shared__ bf16 Bs[128 * 32];

  const int t = threadIdx.x;
  const int bn = blockIdx.x, bm = blockIdx.y;
  const int w = t >> 6, l = t & 63, g = l >> 4, q = l & 15;
  const int wr = w >> 1, wc = w & 1;

  f32x4 acc[4][4];
  #pragma unroll
  for (int i = 0; i < 4; ++i)
    #pragma unroll
    for (int j = 0; j < 4; ++j)
      #pragma unroll
      for (int r = 0; r < 4; ++r) acc[i][j][r] = 0.f;

  char* lA0 = (char*)As + w * 1024;
  char* lA1 = (char*)As + 4096 + w * 1024;
  char* lB0 = (char*)Bs + w * 1024;
  char* lB1 = (char*)Bs + 4096 + w * 1024;
  const char* gA0 = (const char*)(A + (size_t)(bm * 128 + (t >> 2)) * K) + (t & 3) * 16;
  const char* gA1 = gA0 + (size_t)64 * K * 2;
  const char* gB0 = (const char*)(B + (size_t)(bn * 128 + (t >> 2)) * K) + (t & 3) * 16;
  const char* gB1 = gB0 + (size_t)64 * K * 2;

  for (int k0 = 0; k0 < K; k0 += 32) {
    const int kb = k0 * 2;
    gload_lds16(gA0 + kb, lA0);
    gload_lds16(gA1 + kb, lA1);
    gload_lds16(gB0 + kb, lB0);
    gload_lds16(gB1 + kb, lB1);
    __syncthreads();
    bf16x8 a[4], b[4];
    #pragma unroll
    for (int mi = 0; mi < 4; ++mi)
      a[mi] = *(const bf16x8*)&As[(wr * 64 + mi * 16 + q) * 32 + g * 8];
    #pragma unroll
    for (int ni = 0; ni < 4; ++ni)
      b[ni] = *(const bf16x8*)&Bs[(wc * 64 + ni * 16 + q) * 32 + g * 8];
    #pragma unroll
    for (int mi = 0; mi < 4; ++mi)
      #pragma unroll
      for (int ni = 0; ni < 4; ++ni)
        acc[mi][ni] = __builtin_amdgcn_mfma_f32_16x16x32_bf16(a[mi], b[ni], acc[mi][ni], 0, 0, 0);
    __syncthreads();
  }

  #pragma unroll
  for (int mi = 0; mi < 4; ++mi) {
    #pragma unroll
    for (int r = 0; r < 4; ++r) {
      const long row = bm * 128 + wr * 64 + mi * 16 + g * 4 + r;
      #pragma unroll
      for (int ni = 0; ni < 4; ++ni) {
        const int col = bn * 128 + wc * 64 + ni * 16 + q;
        if (col < Nvalid) C[row * ldc + col] = acc[mi][ni][r];
      }
    }
  }
}

// ---------------- combine per-row partials -> NLL ----------------
__global__ __launch_bounds__(64) void k_combine(const float* __restrict__ pmax,
                                                const float* __restrict__ psum,
                                                const float* __restrict__ ptgt,
                                                float* __restrict__ nll,
                                                int ntiles, int nv) {
  const int r = blockIdx.x;
  const int l = threadIdx.x;
  float M = -1e30f, Ssum = 0.f;
  for (int tl = l; tl < ntiles; tl += 64) {
    const float m = pmax[(size_t)r * ntiles + tl];
    const float s = psum[(size_t)r * ntiles + tl];
    const float nM = fmaxf(M, m);
    Ssum = Ssum * __expf(M - nM) + s * __expf(m - nM);
    M = nM;
  }
  #pragma unroll
  for (int d = 1; d < 64; d <<= 1) {
    const float m2 = __shfl_xor(M, d, 64);
    const float s2 = __shfl_xor(Ssum, d, 64);
    const float nM = fmaxf(M, m2);
    Ssum = Ssum * __expf(M - nM) + s2 * __expf(m2 - nM);
    M = nM;
  }
  if (l == 0) nll[r] = (r < nv) ? (M + logf(Ssum) - ptgt[r]) : 0.f;
}

// ---------------- final loss ----------------
__global__ __launch_bounds__(256) void k_loss(const float* __restrict__ nll,
                                              float* __restrict__ out) {
  __shared__ float sh[256];
  const int t = threadIdx.x;
  float sums[3];
  #pragma unroll
  for (int h = 0; h < 3; ++h) {
    const int nv = 2047 - h;
    float s = 0.f;
    for (int r = t; r < nv; r += 256) s += nll[h * 2048 + r];
    sh[t] = s; __syncthreads();
    for (int off = 128; off > 0; off >>= 1) {
      if (t < off) sh[t] += sh[t + off];
      __syncthreads();
    }
    sums[h] = sh[0]; __syncthreads();
  }
  if (t == 0)
    out[0] = sums[0] / 2047.f + 0.3f * 0.5f * (sums[1] / 2046.f + sums[2] / 2045.f);
}

extern "C" void kernel_launch(void* const* d_in, const int* in_sizes, int n_in,
                              void* d_out, int out_size, void* d_ws, size_t ws_size,
                              hipStream_t stream) {
  const float* hidden      = (const float*)d_in[0];
  const int*   targets     = (const int*)d_in[1];
  const float* emb_w       = (const float*)d_in[2];
  const float* main_norm_w = (const float*)d_in[3];
  const float* aux_proj_w  = (const float*)d_in[4];
  const float* aux_norm_w  = (const float*)d_in[5];
  const float* aux_out_w   = (const float*)d_in[6];
  float* out = (float*)d_out;

  char* ws = (char*)d_ws;
  bf16*  Wb    = (bf16*)(ws);                   // [VPAD2][1024] bf16
  bf16*  hb    = (bf16*)(ws + 104857600);       // hidden bf16
  bf16*  xn    = (bf16*)(ws + 109051904);       // normalized input bf16
  bf16*  projb = (bf16*)(ws + 113246208);       // aux proj weights bf16
  float* hbuf  = (float*)(ws + 117440512);      // aux pre-norm f32
  float* pmax  = (float*)(ws + 125829120);      // [2048][200]
  float* psum  = (float*)(ws + 127467520);      // [2048][200]
  float* ptgt  = (float*)(ws + 129105920);      // [2048]
  float* nll   = (float*)(ws + 129114112);      // [3][2048]

  // prep
  k_cvt<<<2048, 256, 0, stream>>>(hidden, hb, 2048, 2048);
  k_cvt<<<2048, 256, 0, stream>>>(aux_proj_w, projb, 2048, 2048);
  k_rms<<<2048, 256, 0, stream>>>(hidden, main_norm_w, xn);

  // ---- main head ----
  k_cvt<<<2048, 256, 0, stream>>>(emb_w, Wb, VOCAB, VPAD2);
  k_gemm256<true><<<1600, 512, 0, stream>>>(
      xn, Wb, out, VOCAB, VOCAB, targets, 1, pmax, psum, ptgt, NT256);
  k_combine<<<2048, 64, 0, stream>>>(pmax, psum, ptgt, nll, NT256, 2047);

  // ---- aux heads ----
  for (int i = 0; i < 2; ++i) {
    k_cvt<<<2048, 256, 0, stream>>>(aux_out_w + (size_t)i * VOCAB * DMODEL, Wb, VOCAB, VPAD2);
    k_gemm<<<dim3(8, 16), 256, 0, stream>>>(
        hb, projb + (size_t)i * DMODEL * DMODEL, hbuf, DMODEL, DMODEL);
    k_rms<<<2048, 256, 0, stream>>>(hbuf, aux_norm_w + (size_t)i * DMODEL, xn);
    k_gemm256<false><<<1600, 512, 0, stream>>>(
        xn, Wb, nullptr, 0, VOCAB, targets, i + 2, pmax, psum, ptgt, NT256);
    k_combine<<<2048, 64, 0, stream>>>(pmax, psum, ptgt, nll + (i + 1) * 2048, NT256, 2048 - (i + 2));
  }

  k_loss<<<1, 256, 0, stream>>>(nll, out + (size_t)S_LEN * VOCAB);
}

// Round 10
// 1146.170 us; speedup vs baseline: 1.3004x; 1.3004x over previous
//
#include <hip/hip_runtime.h>
#include <hip/hip_bf16.h>

// MultiTokenPrediction: main head logits + fused CE for main + 2 aux heads.
// B=1, S=2048, D=1024, V=50257, heads predict t+1 (main), t+2, t+3 (aux).

typedef __hip_bfloat16 bf16;
typedef __attribute__((ext_vector_type(8))) short bf16x8;
typedef __attribute__((ext_vector_type(4))) float f32x4;

typedef const __attribute__((address_space(1))) void* gptr_t;
typedef __attribute__((address_space(3))) void* lptr_t;

#define S_LEN   2048
#define DMODEL  1024
#define VOCAB   50257
#define VPAD2   51200   // 400*128 padded N
#define NT128   400     // VPAD2/128

__device__ __forceinline__ void gload_lds16(const void* g, void* l) {
  __builtin_amdgcn_global_load_lds((gptr_t)g, (lptr_t)l, 16, 0, 0);
}

// ---------------- f32 -> bf16 conversion with row zero-padding ----------------
__global__ __launch_bounds__(256) void k_cvt(const float* __restrict__ src,
                                             bf16* __restrict__ dst,
                                             long rows_src, long rows_pad) {
  const long total4 = rows_pad << 8;
  for (long i = (long)blockIdx.x * 256 + threadIdx.x; i < total4;
       i += (long)gridDim.x * 256) {
    const long e = i << 2;
    const long row = e >> 10;
    alignas(8) bf16 o[4];
    if (row < rows_src) {
      const float4 v = *(const float4*)(src + e);
      o[0] = __float2bfloat16(v.x); o[1] = __float2bfloat16(v.y);
      o[2] = __float2bfloat16(v.z); o[3] = __float2bfloat16(v.w);
    } else {
      o[0] = o[1] = o[2] = o[3] = __float2bfloat16(0.f);
    }
    *(uint2*)(dst + e) = *(const uint2*)o;
  }
}

// ---------------- RMSNorm row kernel: f32 in, bf16 out ----------------
__global__ __launch_bounds__(256) void k_rms(const float* __restrict__ x,
                                             const float* __restrict__ w,
                                             bf16* __restrict__ xn) {
  const int row = blockIdx.x;
  const int t = threadIdx.x;
  const float4 v = ((const float4*)(x + (size_t)row * DMODEL))[t];
  float ss = v.x*v.x + v.y*v.y + v.z*v.z + v.w*v.w;
  #pragma unroll
  for (int d = 1; d < 64; d <<= 1) ss += __shfl_xor(ss, d, 64);
  __shared__ float red[4];
  if ((t & 63) == 0) red[t >> 6] = ss;
  __syncthreads();
  const float tot = red[0] + red[1] + red[2] + red[3];
  const float scale = rsqrtf(tot * (1.f / DMODEL) + 1e-5f);
  const float4 wv = ((const float4*)w)[t];
  alignas(8) bf16 o[4];
  o[0] = __float2bfloat16(v.x * scale * wv.x);
  o[1] = __float2bfloat16(v.y * scale * wv.y);
  o[2] = __float2bfloat16(v.z * scale * wv.z);
  o[3] = __float2bfloat16(v.w * scale * wv.w);
  *(uint2*)(xn + (size_t)row * DMODEL + t * 4) = *(const uint2*)o;
}

// ======== 128x128 bf16 MFMA GEMM (R1 structure + XCD grid + swizzle) ========
// C[m][n] = sum_k A[m][k]*B[n][k]. A:[2048][1024], B:[VPAD2][1024] bf16.
// WHY 128^2: R1 measured 394us for main-with-C-write at Occupancy 43.9%
// (~3.5 blocks/CU TLP) despite 9x B-overfetch + 2.6e7 bank conflicts -- it
// beat every 1-block/CU 256^2 variant (412-521us, R2-R9). 256^2 cannot
// exceed 1 block/CU (acc=128 VGPR; R7 spill proved the cap). This round
// keeps R1's loop and fixes its two measured pathologies:
//  (1) grid 6400: xcd=id&7, bm=(id>>3)&15, bn=xcd*50+(id>>7). Each XCD owns
//      50 bn-columns; 16 bm-siblings dispatch consecutively on one XCD ->
//      B-tile fetched ~once (R4-verified mechanism, FETCH 927->166MB there).
//  (2) st_16x32 XOR swizzle on the per-wave 1KB [16r][32c] LDS subtiles
//      (byte-identical pattern to R3/R4, verified conflict-free): read byte
//      (q*64+g*16)^((q>>3&1)<<5); DMA source col pre-swizzled
//      ((t&3)*16)^((t>>5&1)*32) bytes; DMA dest linear (rule #21).
// CE partials fused in epilogue (per-row max/sumexp over the 128-col tile).
template<bool WRITE_OUT>
__global__ __launch_bounds__(256, 2)
void k_gemm128(const bf16* __restrict__ A, const bf16* __restrict__ B,
               float* __restrict__ C, long ldc, int Nvalid,
               const int* __restrict__ targets, int shift,
               float* __restrict__ pmax, float* __restrict__ psum,
               float* __restrict__ ptgt, int ntiles) {
  constexpr int K = DMODEL;
  __shared__ bf16 As[128 * 32];
  __shared__ bf16 Bs[128 * 32];
  __shared__ float lds_m[128][2];
  __shared__ float lds_s[128][2];
  __shared__ int lds_tgt[128];

  const int t = threadIdx.x;
  const int w = t >> 6, l = t & 63, g = l >> 4, q = l & 15;
  const int wr = w >> 1, wc = w & 1;
  const int id = blockIdx.x;
  const int bm = (id >> 3) & 15;
  const int bn = (id & 7) * 50 + (id >> 7);

  f32x4 acc[4][4];
  #pragma unroll
  for (int i = 0; i < 4; ++i)
    #pragma unroll
    for (int j = 0; j < 4; ++j)
      #pragma unroll
      for (int r = 0; r < 4; ++r) acc[i][j][r] = 0.f;

  // LDS staging dests (linear; wave w fills subtile w and 4+w of each array)
  char* lA0 = (char*)As + w * 1024;
  char* lA1 = (char*)As + 4096 + w * 1024;
  char* lB0 = (char*)Bs + w * 1024;
  char* lB1 = (char*)Bs + 4096 + w * 1024;
  // global sources, col pre-swizzled (bytes)
  const int scol = ((t & 3) * 16) ^ (((t >> 5) & 1) * 32);
  const char* gA0 = (const char*)(A + (size_t)(bm * 128 + (t >> 2)) * K) + scol;
  const char* gA1 = gA0 + (size_t)64 * K * 2;
  const char* gB0 = (const char*)(B + (size_t)(bn * 128 + (t >> 2)) * K) + scol;
  const char* gB1 = gB0 + (size_t)64 * K * 2;

  // frag-read bases (swizzled; verified-conflict-free pattern)
  const int laneoff = (q * 64 + g * 16) ^ (((q >> 3) & 1) << 5);
  const char* rdA = (const char*)As + wr * 4096 + laneoff;
  const char* rdB = (const char*)Bs + wc * 4096 + laneoff;

  for (int k0 = 0; k0 < K; k0 += 32) {
    const int kb = k0 * 2;
    gload_lds16(gA0 + kb, lA0);
    gload_lds16(gA1 + kb, lA1);
    gload_lds16(gB0 + kb, lB0);
    gload_lds16(gB1 + kb, lB1);
    __syncthreads();
    bf16x8 a[4], b[4];
    #pragma unroll
    for (int mi = 0; mi < 4; ++mi) a[mi] = *(const bf16x8*)(rdA + mi * 1024);
    #pragma unroll
    for (int ni = 0; ni < 4; ++ni) b[ni] = *(const bf16x8*)(rdB + ni * 1024);
    __builtin_amdgcn_s_setprio(1);
    #pragma unroll
    for (int mi = 0; mi < 4; ++mi)
      #pragma unroll
      for (int ni = 0; ni < 4; ++ni)
        acc[mi][ni] = __builtin_amdgcn_mfma_f32_16x16x32_bf16(a[mi], b[ni], acc[mi][ni], 0, 0, 0);
    __builtin_amdgcn_s_setprio(0);
    __syncthreads();
  }

  // ---------------- epilogue: C write ----------------
  if constexpr (WRITE_OUT) {
    #pragma unroll
    for (int mi = 0; mi < 4; ++mi) {
      #pragma unroll
      for (int r = 0; r < 4; ++r) {
        const long row = bm * 128 + wr * 64 + mi * 16 + g * 4 + r;
        #pragma unroll
        for (int ni = 0; ni < 4; ++ni) {
          const int col = bn * 128 + wc * 64 + ni * 16 + q;
          if (col < Nvalid) C[row * ldc + col] = acc[mi][ni][r];
        }
      }
    }
  }

  // ---------------- fused CE partials ----------------
  if (t < 128) {
    const int rowg = bm * 128 + t;
    lds_tgt[t] = (rowg < S_LEN - shift) ? targets[rowg + shift] : -1;
  }
  __syncthreads();
  #pragma unroll
  for (int mi = 0; mi < 4; ++mi) {
    #pragma unroll
    for (int r = 0; r < 4; ++r) {
      const int rl = wr * 64 + mi * 16 + g * 4 + r;
      const int tgt = lds_tgt[rl];
      float v[4];
      #pragma unroll
      for (int ni = 0; ni < 4; ++ni) {
        const int n = bn * 128 + wc * 64 + ni * 16 + q;
        const float av = acc[mi][ni][r];
        if (n == tgt) ptgt[bm * 128 + rl] = av;
        v[ni] = (n < Nvalid) ? av : -1e30f;
      }
      float m = fmaxf(fmaxf(v[0], v[1]), fmaxf(v[2], v[3]));
      #pragma unroll
      for (int d = 1; d < 16; d <<= 1) m = fmaxf(m, __shfl_xor(m, d, 64));
      float s = 0.f;
      #pragma unroll
      for (int ni = 0; ni < 4; ++ni) s += __expf(v[ni] - m);
      #pragma unroll
      for (int d = 1; d < 16; d <<= 1) s += __shfl_xor(s, d, 64);
      if (q == 0) { lds_m[rl][wc] = m; lds_s[rl][wc] = s; }
    }
  }
  __syncthreads();
  if (t < 128) {
    const float m0 = lds_m[t][0], m1 = lds_m[t][1];
    const float s0 = lds_s[t][0], s1 = lds_s[t][1];
    const float M = fmaxf(m0, m1);
    const float Ssum = s0 * __expf(m0 - M) + s1 * __expf(m1 - M);
    const size_t idx = (size_t)(bm * 128 + t) * ntiles + bn;
    pmax[idx] = M;
    psum[idx] = Ssum;
  }
}

// ---------------- 128x128 GEMM (small d->d projection) ----------------
__global__ __launch_bounds__(256, 2)
void k_gemm(const bf16* __restrict__ A, const bf16* __restrict__ B,
            float* __restrict__ C, long ldc, int Nvalid) {
  constexpr int K = DMODEL;
  __shared__ bf16 As[128 * 32];
  __shared__ bf16 Bs[128 * 32];

  const int t = threadIdx.x;
  const int bn = blockIdx.x, bm = blockIdx.y;
  const int w = t >> 6, l = t & 63, g = l >> 4, q = l & 15;
  const int wr = w >> 1, wc = w & 1;

  f32x4 acc[4][4];
  #pragma unroll
  for (int i = 0; i < 4; ++i)
    #pragma unroll
    for (int j = 0; j < 4; ++j)
      #pragma unroll
      for (int r = 0; r < 4; ++r) acc[i][j][r] = 0.f;

  char* lA0 = (char*)As + w * 1024;
  char* lA1 = (char*)As + 4096 + w * 1024;
  char* lB0 = (char*)Bs + w * 1024;
  char* lB1 = (char*)Bs + 4096 + w * 1024;
  const char* gA0 = (const char*)(A + (size_t)(bm * 128 + (t >> 2)) * K) + (t & 3) * 16;
  const char* gA1 = gA0 + (size_t)64 * K * 2;
  const char* gB0 = (const char*)(B + (size_t)(bn * 128 + (t >> 2)) * K) + (t & 3) * 16;
  const char* gB1 = gB0 + (size_t)64 * K * 2;

  for (int k0 = 0; k0 < K; k0 += 32) {
    const int kb = k0 * 2;
    gload_lds16(gA0 + kb, lA0);
    gload_lds16(gA1 + kb, lA1);
    gload_lds16(gB0 + kb, lB0);
    gload_lds16(gB1 + kb, lB1);
    __syncthreads();
    bf16x8 a[4], b[4];
    #pragma unroll
    for (int mi = 0; mi < 4; ++mi)
      a[mi] = *(const bf16x8*)&As[(wr * 64 + mi * 16 + q) * 32 + g * 8];
    #pragma unroll
    for (int ni = 0; ni < 4; ++ni)
      b[ni] = *(const bf16x8*)&Bs[(wc * 64 + ni * 16 + q) * 32 + g * 8];
    #pragma unroll
    for (int mi = 0; mi < 4; ++mi)
      #pragma unroll
      for (int ni = 0; ni < 4; ++ni)
        acc[mi][ni] = __builtin_amdgcn_mfma_f32_16x16x32_bf16(a[mi], b[ni], acc[mi][ni], 0, 0, 0);
    __syncthreads();
  }

  #pragma unroll
  for (int mi = 0; mi < 4; ++mi) {
    #pragma unroll
    for (int r = 0; r < 4; ++r) {
      const long row = bm * 128 + wr * 64 + mi * 16 + g * 4 + r;
      #pragma unroll
      for (int ni = 0; ni < 4; ++ni) {
        const int col = bn * 128 + wc * 64 + ni * 16 + q;
        if (col < Nvalid) C[row * ldc + col] = acc[mi][ni][r];
      }
    }
  }
}

// ---------------- combine per-row partials -> NLL ----------------
__global__ __launch_bounds__(64) void k_combine(const float* __restrict__ pmax,
                                                const float* __restrict__ psum,
                                                const float* __restrict__ ptgt,
                                                float* __restrict__ nll,
                                                int ntiles, int nv) {
  const int r = blockIdx.x;
  const int l = threadIdx.x;
  float M = -1e30f, Ssum = 0.f;
  for (int tl = l; tl < ntiles; tl += 64) {
    const float m = pmax[(size_t)r * ntiles + tl];
    const float s = psum[(size_t)r * ntiles + tl];
    const float nM = fmaxf(M, m);
    Ssum = Ssum * __expf(M - nM) + s * __expf(m - nM);
    M = nM;
  }
  #pragma unroll
  for (int d = 1; d < 64; d <<= 1) {
    const float m2 = __shfl_xor(M, d, 64);
    const float s2 = __shfl_xor(Ssum, d, 64);
    const float nM = fmaxf(M, m2);
    Ssum = Ssum * __expf(M - nM) + s2 * __expf(m2 - nM);
    M = nM;
  }
  if (l == 0) nll[r] = (r < nv) ? (M + logf(Ssum) - ptgt[r]) : 0.f;
}

// ---------------- final loss ----------------
__global__ __launch_bounds__(256) void k_loss(const float* __restrict__ nll,
                                              float* __restrict__ out) {
  __shared__ float sh[256];
  const int t = threadIdx.x;
  float sums[3];
  #pragma unroll
  for (int h = 0; h < 3; ++h) {
    const int nv = 2047 - h;
    float s = 0.f;
    for (int r = t; r < nv; r += 256) s += nll[h * 2048 + r];
    sh[t] = s; __syncthreads();
    for (int off = 128; off > 0; off >>= 1) {
      if (t < off) sh[t] += sh[t + off];
      __syncthreads();
    }
    sums[h] = sh[0]; __syncthreads();
  }
  if (t == 0)
    out[0] = sums[0] / 2047.f + 0.3f * 0.5f * (sums[1] / 2046.f + sums[2] / 2045.f);
}

extern "C" void kernel_launch(void* const* d_in, const int* in_sizes, int n_in,
                              void* d_out, int out_size, void* d_ws, size_t ws_size,
                              hipStream_t stream) {
  const float* hidden      = (const float*)d_in[0];
  const int*   targets     = (const int*)d_in[1];
  const float* emb_w       = (const float*)d_in[2];
  const float* main_norm_w = (const float*)d_in[3];
  const float* aux_proj_w  = (const float*)d_in[4];
  const float* aux_norm_w  = (const float*)d_in[5];
  const float* aux_out_w   = (const float*)d_in[6];
  float* out = (float*)d_out;

  char* ws = (char*)d_ws;
  bf16*  Wb    = (bf16*)(ws);                   // [VPAD2][1024] bf16, 104,857,600 B
  bf16*  hb    = (bf16*)(ws + 104857600);       // hidden bf16, 4 MiB
  bf16*  xn    = (bf16*)(ws + 109051904);       // normalized input bf16, 4 MiB
  bf16*  projb = (bf16*)(ws + 113246208);       // aux proj weights bf16, 4 MiB
  float* hbuf  = (float*)(ws + 117440512);      // aux pre-norm f32, 8 MiB
  float* pmax  = (float*)(ws + 125829120);      // [2048][400] f32, 3,276,800 B
  float* psum  = (float*)(ws + 129105920);      // [2048][400] f32
  float* ptgt  = (float*)(ws + 132382720);      // [2048]
  float* nll   = (float*)(ws + 132390912);      // [3][2048]

  // prep
  k_cvt<<<2048, 256, 0, stream>>>(hidden, hb, 2048, 2048);
  k_cvt<<<2048, 256, 0, stream>>>(aux_proj_w, projb, 2048, 2048);
  k_rms<<<2048, 256, 0, stream>>>(hidden, main_norm_w, xn);

  // ---- main head ----
  k_cvt<<<2048, 256, 0, stream>>>(emb_w, Wb, VOCAB, VPAD2);
  k_gemm128<true><<<6400, 256, 0, stream>>>(
      xn, Wb, out, VOCAB, VOCAB, targets, 1, pmax, psum, ptgt, NT128);
  k_combine<<<2048, 64, 0, stream>>>(pmax, psum, ptgt, nll, NT128, 2047);

  // ---- aux heads ----
  for (int i = 0; i < 2; ++i) {
    k_cvt<<<2048, 256, 0, stream>>>(aux_out_w + (size_t)i * VOCAB * DMODEL, Wb, VOCAB, VPAD2);
    k_gemm<<<dim3(8, 16), 256, 0, stream>>>(
        hb, projb + (size_t)i * DMODEL * DMODEL, hbuf, DMODEL, DMODEL);
    k_rms<<<2048, 256, 0, stream>>>(hbuf, aux_norm_w + (size_t)i * DMODEL, xn);
    k_gemm128<false><<<6400, 256, 0, stream>>>(
        xn, Wb, nullptr, 0, VOCAB, targets, i + 2, pmax, psum, ptgt, NT128);
    k_combine<<<2048, 64, 0, stream>>>(pmax, psum, ptgt, nll + (i + 1) * 2048, NT128, 2048 - (i + 2));
  }

  k_loss<<<1, 256, 0, stream>>>(nll, out + (size_t)S_LEN * VOCAB);
}

// Round 11
// 1029.256 us; speedup vs baseline: 1.4482x; 1.1136x over previous
//
#include <hip/hip_runtime.h>
#include <hip/hip_bf16.h>

// MultiTokenPrediction: main head logits + fused CE for main + 2 aux heads.
// B=1, S=2048, D=1024, V=50257, heads predict t+1 (main), t+2, t+3 (aux).

typedef __hip_bfloat16 bf16;
typedef __attribute__((ext_vector_type(8))) short bf16x8;
typedef __attribute__((ext_vector_type(4))) float f32x4;

typedef const __attribute__((address_space(1))) void* gptr_t;
typedef __attribute__((address_space(3))) void* lptr_t;

#define S_LEN   2048
#define DMODEL  1024
#define VOCAB   50257
#define NPADR   50304   // 393*128 padded rows for Wb
#define NT128   393
#define NBLK    6288    // 8*49*16 + 16

__device__ __forceinline__ void gload_lds16(const void* g, void* l) {
  __builtin_amdgcn_global_load_lds((gptr_t)g, (lptr_t)l, 16, 0, 0);
}

// ---------------- f32 -> bf16 conversion with row zero-padding ----------------
__global__ __launch_bounds__(256) void k_cvt(const float* __restrict__ src,
                                             bf16* __restrict__ dst,
                                             long rows_src, long rows_pad) {
  const long total4 = rows_pad << 8;
  for (long i = (long)blockIdx.x * 256 + threadIdx.x; i < total4;
       i += (long)gridDim.x * 256) {
    const long e = i << 2;
    const long row = e >> 10;
    alignas(8) bf16 o[4];
    if (row < rows_src) {
      const float4 v = *(const float4*)(src + e);
      o[0] = __float2bfloat16(v.x); o[1] = __float2bfloat16(v.y);
      o[2] = __float2bfloat16(v.z); o[3] = __float2bfloat16(v.w);
    } else {
      o[0] = o[1] = o[2] = o[3] = __float2bfloat16(0.f);
    }
    *(uint2*)(dst + e) = *(const uint2*)o;
  }
}

// ---------------- RMSNorm row kernel: f32 in, bf16 out ----------------
__global__ __launch_bounds__(256) void k_rms(const float* __restrict__ x,
                                             const float* __restrict__ w,
                                             bf16* __restrict__ xn) {
  const int row = blockIdx.x;
  const int t = threadIdx.x;
  const float4 v = ((const float4*)(x + (size_t)row * DMODEL))[t];
  float ss = v.x*v.x + v.y*v.y + v.z*v.z + v.w*v.w;
  #pragma unroll
  for (int d = 1; d < 64; d <<= 1) ss += __shfl_xor(ss, d, 64);
  __shared__ float red[4];
  if ((t & 63) == 0) red[t >> 6] = ss;
  __syncthreads();
  const float tot = red[0] + red[1] + red[2] + red[3];
  const float scale = rsqrtf(tot * (1.f / DMODEL) + 1e-5f);
  const float4 wv = ((const float4*)w)[t];
  alignas(8) bf16 o[4];
  o[0] = __float2bfloat16(v.x * scale * wv.x);
  o[1] = __float2bfloat16(v.y * scale * wv.y);
  o[2] = __float2bfloat16(v.z * scale * wv.z);
  o[3] = __float2bfloat16(v.w * scale * wv.w);
  *(uint2*)(xn + (size_t)row * DMODEL + t * 4) = *(const uint2*)o;
}

// ======== 128x128 bf16 MFMA GEMM (R10 winner + BK=64 + nt-store + NT393) ========
// C[m][n] = sum_k A[m][k]*B[n][k]. A:[2048][1024], B:[NPADR][1024] bf16.
// R10 measured: conflicts 0, FETCH 296MB, 377us main / ~270us aux (~795 TF =
// m97-structure ceiling). This round: (1) BK=64 halves barrier count (16 steps
// x 32 MFMA; LDS 32KB as 2x 8KB half-arrays per operand, same verified
// [16r][32c]-subtile st_16x32 swizzle per half); (2) nontemporal C stores
// (partial-line f32 stores at ldc=50257 were read-allocating ~190MB of RMW
// FETCH); (3) 393 tiles instead of 400 (-1.75% padded work), non-uniform XCD
// map: ids 0..6271: xcd=id&7 owns 49 bn-cols x16 bm consecutive; tail 16 ids
// cover col 392. CE partials fused in epilogue.
template<bool WRITE_OUT>
__global__ __launch_bounds__(256, 2)
void k_gemm128(const bf16* __restrict__ A, const bf16* __restrict__ B,
               float* __restrict__ C, long ldc, int Nvalid,
               const int* __restrict__ targets, int shift,
               float* __restrict__ pmax, float* __restrict__ psum,
               float* __restrict__ ptgt, int ntiles) {
  __shared__ bf16 As[2][128 * 32];   // k-half 0 / 1, each 8 subtiles of [16][32]
  __shared__ bf16 Bs[2][128 * 32];
  __shared__ float lds_m[128][2];
  __shared__ float lds_s[128][2];
  __shared__ int lds_tgt[128];

  const int t = threadIdx.x;
  const int w = t >> 6, l = t & 63, g = l >> 4, q = l & 15;
  const int wr = w >> 1, wc = w & 1;
  const int id = blockIdx.x;
  int bm, bn;
  if (id < 6272) {
    const int x = id & 7, u = id >> 3;
    bm = u & 15;
    bn = x * 49 + (u >> 4);
  } else {
    bm = id - 6272;
    bn = 392;
  }

  f32x4 acc[4][4];
  #pragma unroll
  for (int i = 0; i < 4; ++i)
    #pragma unroll
    for (int j = 0; j < 4; ++j)
      #pragma unroll
      for (int r = 0; r < 4; ++r) acc[i][j][r] = 0.f;

  // staging dests (linear; wave w fills subtiles w and 4+w of each half-array)
  char* dA = (char*)As + w * 1024;
  char* dB = (char*)Bs + w * 1024;
  // global sources, col pre-swizzled (bytes within the 64-byte k-half row)
  const int scol = ((t & 3) * 16) ^ (((t >> 5) & 1) * 32);
  const char* gA0 = (const char*)(A + (size_t)(bm * 128 + (t >> 2)) * DMODEL) + scol;
  const char* gA1 = gA0 + (size_t)64 * DMODEL * 2;
  const char* gB0 = (const char*)(B + (size_t)(bn * 128 + (t >> 2)) * DMODEL) + scol;
  const char* gB1 = gB0 + (size_t)64 * DMODEL * 2;

  // frag-read bases (st_16x32-swizzled; verified conflict-free R3/R10)
  const int laneoff = (q * 64 + g * 16) ^ (((q >> 3) & 1) << 5);
  const char* rdA = (const char*)As + wr * 4096 + laneoff;
  const char* rdB = (const char*)Bs + wc * 4096 + laneoff;

  for (int k0 = 0; k0 < 16; ++k0) {
    const int kb = k0 * 128;         // byte offset of this 64-col K-step
    // k-half 0 (cols +0) and k-half 1 (cols +32 -> +64 bytes), A then B
    gload_lds16(gA0 + kb, dA);
    gload_lds16(gA1 + kb, dA + 4096);
    gload_lds16(gA0 + kb + 64, dA + 8192);
    gload_lds16(gA1 + kb + 64, dA + 12288);
    gload_lds16(gB0 + kb, dB);
    gload_lds16(gB1 + kb, dB + 4096);
    gload_lds16(gB0 + kb + 64, dB + 8192);
    gload_lds16(gB1 + kb + 64, dB + 12288);
    __syncthreads();
    bf16x8 a[4], b[4];
    // ---- k-half 0 ----
    #pragma unroll
    for (int mi = 0; mi < 4; ++mi) a[mi] = *(const bf16x8*)(rdA + mi * 1024);
    #pragma unroll
    for (int ni = 0; ni < 4; ++ni) b[ni] = *(const bf16x8*)(rdB + ni * 1024);
    __builtin_amdgcn_s_setprio(1);
    #pragma unroll
    for (int mi = 0; mi < 4; ++mi)
      #pragma unroll
      for (int ni = 0; ni < 4; ++ni)
        acc[mi][ni] = __builtin_amdgcn_mfma_f32_16x16x32_bf16(a[mi], b[ni], acc[mi][ni], 0, 0, 0);
    __builtin_amdgcn_s_setprio(0);
    // ---- k-half 1 ----
    #pragma unroll
    for (int mi = 0; mi < 4; ++mi) a[mi] = *(const bf16x8*)(rdA + 8192 + mi * 1024);
    #pragma unroll
    for (int ni = 0; ni < 4; ++ni) b[ni] = *(const bf16x8*)(rdB + 8192 + ni * 1024);
    __builtin_amdgcn_s_setprio(1);
    #pragma unroll
    for (int mi = 0; mi < 4; ++mi)
      #pragma unroll
      for (int ni = 0; ni < 4; ++ni)
        acc[mi][ni] = __builtin_amdgcn_mfma_f32_16x16x32_bf16(a[mi], b[ni], acc[mi][ni], 0, 0, 0);
    __builtin_amdgcn_s_setprio(0);
    __syncthreads();
  }

  // ---------------- epilogue: C write (nontemporal: avoid RMW read-allocate) ----------------
  if constexpr (WRITE_OUT) {
    #pragma unroll
    for (int mi = 0; mi < 4; ++mi) {
      #pragma unroll
      for (int r = 0; r < 4; ++r) {
        const long row = bm * 128 + wr * 64 + mi * 16 + g * 4 + r;
        #pragma unroll
        for (int ni = 0; ni < 4; ++ni) {
          const int col = bn * 128 + wc * 64 + ni * 16 + q;
          if (col < Nvalid)
            __builtin_nontemporal_store(acc[mi][ni][r], &C[row * ldc + col]);
        }
      }
    }
  }

  // ---------------- fused CE partials ----------------
  if (t < 128) {
    const int rowg = bm * 128 + t;
    lds_tgt[t] = (rowg < S_LEN - shift) ? targets[rowg + shift] : -1;
  }
  __syncthreads();
  #pragma unroll
  for (int mi = 0; mi < 4; ++mi) {
    #pragma unroll
    for (int r = 0; r < 4; ++r) {
      const int rl = wr * 64 + mi * 16 + g * 4 + r;
      const int tgt = lds_tgt[rl];
      float v[4];
      #pragma unroll
      for (int ni = 0; ni < 4; ++ni) {
        const int n = bn * 128 + wc * 64 + ni * 16 + q;
        const float av = acc[mi][ni][r];
        if (n == tgt) ptgt[bm * 128 + rl] = av;
        v[ni] = (n < Nvalid) ? av : -1e30f;
      }
      float m = fmaxf(fmaxf(v[0], v[1]), fmaxf(v[2], v[3]));
      #pragma unroll
      for (int d = 1; d < 16; d <<= 1) m = fmaxf(m, __shfl_xor(m, d, 64));
      float s = 0.f;
      #pragma unroll
      for (int ni = 0; ni < 4; ++ni) s += __expf(v[ni] - m);
      #pragma unroll
      for (int d = 1; d < 16; d <<= 1) s += __shfl_xor(s, d, 64);
      if (q == 0) { lds_m[rl][wc] = m; lds_s[rl][wc] = s; }
    }
  }
  __syncthreads();
  if (t < 128) {
    const float m0 = lds_m[t][0], m1 = lds_m[t][1];
    const float s0 = lds_s[t][0], s1 = lds_s[t][1];
    const float M = fmaxf(m0, m1);
    const float Ssum = s0 * __expf(m0 - M) + s1 * __expf(m1 - M);
    const size_t idx = (size_t)(bm * 128 + t) * ntiles + bn;
    pmax[idx] = M;
    psum[idx] = Ssum;
  }
}

// ---------------- 128x128 GEMM (small d->d projection) ----------------
__global__ __launch_bounds__(256, 2)
void k_gemm(const bf16* __restrict__ A, const bf16* __restrict__ B,
            float* __restrict__ C, long ldc, int Nvalid) {
  constexpr int K = DMODEL;
  __shared__ bf16 As[128 * 32];
  __shared__ bf16 Bs[128 * 32];

  const int t = threadIdx.x;
  const int bn = blockIdx.x, bm = blockIdx.y;
  const int w = t >> 6, l = t & 63, g = l >> 4, q = l & 15;
  const int wr = w >> 1, wc = w & 1;

  f32x4 acc[4][4];
  #pragma unroll
  for (int i = 0; i < 4; ++i)
    #pragma unroll
    for (int j = 0; j < 4; ++j)
      #pragma unroll
      for (int r = 0; r < 4; ++r) acc[i][j][r] = 0.f;

  char* lA0 = (char*)As + w * 1024;
  char* lA1 = (char*)As + 4096 + w * 1024;
  char* lB0 = (char*)Bs + w * 1024;
  char* lB1 = (char*)Bs + 4096 + w * 1024;
  const char* gA0 = (const char*)(A + (size_t)(bm * 128 + (t >> 2)) * K) + (t & 3) * 16;
  const char* gA1 = gA0 + (size_t)64 * K * 2;
  const char* gB0 = (const char*)(B + (size_t)(bn * 128 + (t >> 2)) * K) + (t & 3) * 16;
  const char* gB1 = gB0 + (size_t)64 * K * 2;

  for (int k0 = 0; k0 < K; k0 += 32) {
    const int kb = k0 * 2;
    gload_lds16(gA0 + kb, lA0);
    gload_lds16(gA1 + kb, lA1);
    gload_lds16(gB0 + kb, lB0);
    gload_lds16(gB1 + kb, lB1);
    __syncthreads();
    bf16x8 a[4], b[4];
    #pragma unroll
    for (int mi = 0; mi < 4; ++mi)
      a[mi] = *(const bf16x8*)&As[(wr * 64 + mi * 16 + q) * 32 + g * 8];
    #pragma unroll
    for (int ni = 0; ni < 4; ++ni)
      b[ni] = *(const bf16x8*)&Bs[(wc * 64 + ni * 16 + q) * 32 + g * 8];
    #pragma unroll
    for (int mi = 0; mi < 4; ++mi)
      #pragma unroll
      for (int ni = 0; ni < 4; ++ni)
        acc[mi][ni] = __builtin_amdgcn_mfma_f32_16x16x32_bf16(a[mi], b[ni], acc[mi][ni], 0, 0, 0);
    __syncthreads();
  }

  #pragma unroll
  for (int mi = 0; mi < 4; ++mi) {
    #pragma unroll
    for (int r = 0; r < 4; ++r) {
      const long row = bm * 128 + wr * 64 + mi * 16 + g * 4 + r;
      #pragma unroll
      for (int ni = 0; ni < 4; ++ni) {
        const int col = bn * 128 + wc * 64 + ni * 16 + q;
        if (col < Nvalid) C[row * ldc + col] = acc[mi][ni][r];
      }
    }
  }
}

// ---------------- combine per-row partials -> NLL ----------------
__global__ __launch_bounds__(64) void k_combine(const float* __restrict__ pmax,
                                                const float* __restrict__ psum,
                                                const float* __restrict__ ptgt,
                                                float* __restrict__ nll,
                                                int ntiles, int nv) {
  const int r = blockIdx.x;
  const int l = threadIdx.x;
  float M = -1e30f, Ssum = 0.f;
  for (int tl = l; tl < ntiles; tl += 64) {
    const float m = pmax[(size_t)r * ntiles + tl];
    const float s = psum[(size_t)r * ntiles + tl];
    const float nM = fmaxf(M, m);
    Ssum = Ssum * __expf(M - nM) + s * __expf(m - nM);
    M = nM;
  }
  #pragma unroll
  for (int d = 1; d < 64; d <<= 1) {
    const float m2 = __shfl_xor(M, d, 64);
    const float s2 = __shfl_xor(Ssum, d, 64);
    const float nM = fmaxf(M, m2);
    Ssum = Ssum * __expf(M - nM) + s2 * __expf(m2 - nM);
    M = nM;
  }
  if (l == 0) nll[r] = (r < nv) ? (M + logf(Ssum) - ptgt[r]) : 0.f;
}

// ---------------- final loss ----------------
__global__ __launch_bounds__(256) void k_loss(const float* __restrict__ nll,
                                              float* __restrict__ out) {
  __shared__ float sh[256];
  const int t = threadIdx.x;
  float sums[3];
  #pragma unroll
  for (int h = 0; h < 3; ++h) {
    const int nv = 2047 - h;
    float s = 0.f;
    for (int r = t; r < nv; r += 256) s += nll[h * 2048 + r];
    sh[t] = s; __syncthreads();
    for (int off = 128; off > 0; off >>= 1) {
      if (t < off) sh[t] += sh[t + off];
      __syncthreads();
    }
    sums[h] = sh[0]; __syncthreads();
  }
  if (t == 0)
    out[0] = sums[0] / 2047.f + 0.3f * 0.5f * (sums[1] / 2046.f + sums[2] / 2045.f);
}

extern "C" void kernel_launch(void* const* d_in, const int* in_sizes, int n_in,
                              void* d_out, int out_size, void* d_ws, size_t ws_size,
                              hipStream_t stream) {
  const float* hidden      = (const float*)d_in[0];
  const int*   targets     = (const int*)d_in[1];
  const float* emb_w       = (const float*)d_in[2];
  const float* main_norm_w = (const float*)d_in[3];
  const float* aux_proj_w  = (const float*)d_in[4];
  const float* aux_norm_w  = (const float*)d_in[5];
  const float* aux_out_w   = (const float*)d_in[6];
  float* out = (float*)d_out;

  char* ws = (char*)d_ws;
  bf16*  Wb    = (bf16*)(ws);                   // [NPADR][1024] bf16, 103,022,592 B
  bf16*  hb    = (bf16*)(ws + 104857600);       // hidden bf16, 4 MiB
  bf16*  xn    = (bf16*)(ws + 109051904);       // normalized input bf16, 4 MiB
  bf16*  projb = (bf16*)(ws + 113246208);       // aux proj weights bf16, 4 MiB
  float* hbuf  = (float*)(ws + 117440512);      // aux pre-norm f32, 8 MiB
  float* pmax  = (float*)(ws + 125829120);      // [2048][393] f32
  float* psum  = (float*)(ws + 129105920);      // [2048][393] f32
  float* ptgt  = (float*)(ws + 132382720);      // [2048]
  float* nll   = (float*)(ws + 132390912);      // [3][2048]

  // prep
  k_cvt<<<2048, 256, 0, stream>>>(hidden, hb, 2048, 2048);
  k_cvt<<<2048, 256, 0, stream>>>(aux_proj_w, projb, 2048, 2048);
  k_rms<<<2048, 256, 0, stream>>>(hidden, main_norm_w, xn);

  // ---- main head ----
  k_cvt<<<2048, 256, 0, stream>>>(emb_w, Wb, VOCAB, NPADR);
  k_gemm128<true><<<NBLK, 256, 0, stream>>>(
      xn, Wb, out, VOCAB, VOCAB, targets, 1, pmax, psum, ptgt, NT128);
  k_combine<<<2048, 64, 0, stream>>>(pmax, psum, ptgt, nll, NT128, 2047);

  // ---- aux heads ----
  for (int i = 0; i < 2; ++i) {
    k_cvt<<<2048, 256, 0, stream>>>(aux_out_w + (size_t)i * VOCAB * DMODEL, Wb, VOCAB, NPADR);
    k_gemm<<<dim3(8, 16), 256, 0, stream>>>(
        hb, projb + (size_t)i * DMODEL * DMODEL, hbuf, DMODEL, DMODEL);
    k_rms<<<2048, 256, 0, stream>>>(hbuf, aux_norm_w + (size_t)i * DMODEL, xn);
    k_gemm128<false><<<NBLK, 256, 0, stream>>>(
        xn, Wb, nullptr, 0, VOCAB, targets, i + 2, pmax, psum, ptgt, NT128);
    k_combine<<<2048, 64, 0, stream>>>(pmax, psum, ptgt, nll + (i + 1) * 2048, NT128, 2048 - (i + 2));
  }

  k_loss<<<1, 256, 0, stream>>>(nll, out + (size_t)S_LEN * VOCAB);
}